// Round 4
// baseline (1098.921 us; speedup 1.0000x reference)
//
#include <hip/hip_runtime.h>

// Conv bank of 17 fixed filters + ReLU over (128,1,32768) fp32.
// out[b,j,t] = relu( sum_k W[j,k] * x[b, t + k - 47] ), pad (47,48).
//
//  - rows 0..5  : alternating +-1 filters K=2,4,8,16,32,64 (even taps = -1)
//  - rows 6..11 : exact negations of rows 0..5 (free via relu(-v))
//  - rows 12..16: symmetric quadratic-bump filters, spans 6,12,24,48,96
//
// This version:
//  * R=8 consecutive outputs per thread (TILE=2048): 26 ds_read_b128 per
//    8 outputs; 8 KB contiguous store chunk per (block,row).
//  * Alternating filters via in-register alternating running sum T:
//    each alt output = one subtract of two saved T values (sign folded).
//  * Bump filters direct-FMA from constexpr weight bank (folds to
//    SGPR-held constants; ~186 FMAs/output total across the 5 bumps).
//  * LDS swizzle phys = j + 4*(j>>5): keeps 16B alignment for b128 while
//    spreading the 32B-per-lane stride across banks.
//  * Nontemporal float4 stores (native ext_vector type — HIP float4 is a
//    struct and the builtin rejects it): 285 MB written once, never re-read.

#define S_LEN    32768
#define NFILT    17
#define R        8
#define NTHREADS 256
#define TILE     (R * NTHREADS)     // 2048
#define WIN      (TILE + 96)        // 2144 staged floats
#define NCHUNK   26                 // 104-float window per thread
#define LDS_SZ   2416               // > swz(WIN-1) = 2407

typedef float f32x4 __attribute__((ext_vector_type(4)));

__host__ __device__ constexpr int swz(int j) { return j + 4 * (j >> 5); }

__host__ __device__ constexpr bool neededT(int d) {
    // T indices used by the alt-filter window differences
    return (d >= 17 && d <= 24) || (d >= 33 && d <= 72) || (d >= 81 && d <= 88);
}

struct Bump {
    float w[5][96];
    constexpr Bump() : w{} {
        const int KS[5] = {4, 8, 16, 32, 64};
        for (int f = 0; f < 5; ++f) {
            const int K = KS[f], Q = K / 4;
            const int o = 47 - (3 * K / 2 - 1) / 2;
            for (int j = 0; j < 6 * Q; ++j) {
                const int seg = j / Q, i = j - seg * Q;
                const float t = (seg % 2 == 0) ? (float)(i + 1) / (float)Q
                                               : (float)(Q - i) / (float)Q;
                const float v = t * t;
                w[f][o + j] = (seg == 2 || seg == 3) ? 2.0f * v : -v;
            }
        }
    }
};
__constant__ constexpr Bump BUMP;   // only read with constant indices -> folded

__global__ __launch_bounds__(NTHREADS)
void conv_bank_kernel(const float* __restrict__ x, float* __restrict__ out) {
    __shared__ float xs[LDS_SZ];

    const int tid = threadIdx.x;
    const int ts  = blockIdx.x * TILE;
    const int b   = blockIdx.y;
    const float* __restrict__ xrow = x + (size_t)b * S_LEN;

    // ---- stage tile + halo [ts-48, ts+TILE+48), zero-padded, swizzled ----
#pragma unroll
    for (int j0 = 0; j0 < WIN; j0 += NTHREADS) {
        const int j = j0 + tid;
        if (j0 + NTHREADS <= WIN || j < WIN) {
            const int g = ts - 48 + j;
            xs[swz(j)] = ((unsigned)g < (unsigned)S_LEN) ? xrow[g] : 0.0f;
        }
    }
    __syncthreads();

    // ---- stream the 104-float window: T-chain + bump FMAs ----
    float acc[5][R];
#pragma unroll
    for (int f = 0; f < 5; ++f)
#pragma unroll
        for (int r = 0; r < R; ++r) acc[f][r] = 0.0f;

    float Tv[89];
    float run = 0.0f;
    const int base = R * tid;

#pragma unroll
    for (int c = 0; c < NCHUNK; ++c) {
        const f32x4 xq = *reinterpret_cast<const f32x4*>(&xs[swz(base + 4 * c)]);
        const float xe[4] = {xq.x, xq.y, xq.z, xq.w};
#pragma unroll
        for (int l = 0; l < 4; ++l) {
            const int d = 4 * c + l;            // element index in window
            if (neededT(d)) Tv[d] = run;        // compile-time pruned
            if (d < 88) run += (d & 1) ? -xe[l] : xe[l];
#pragma unroll
            for (int r = 0; r < R; ++r) {
                const int k = d - r - 1;        // bank column for output r
                if (k >= 0 && k < 96) {
#pragma unroll
                    for (int f = 0; f < 5; ++f) {
                        const float wv = BUMP.w[f][k];
                        if (wv != 0.0f) acc[f][r] = fmaf(wv, xe[l], acc[f][r]);
                    }
                }
            }
        }
    }

    // ---- epilogue: relu + nontemporal float4 stores ----
    const int t0 = ts + base;
    float* __restrict__ obase = out + (size_t)b * NFILT * S_LEN + t0;

    auto st = [&](int row, const float (&v)[R]) {
        float* p = obase + (size_t)row * S_LEN;
        f32x4 lo, hi;
        lo.x = fmaxf(v[0], 0.f); lo.y = fmaxf(v[1], 0.f);
        lo.z = fmaxf(v[2], 0.f); lo.w = fmaxf(v[3], 0.f);
        hi.x = fmaxf(v[4], 0.f); hi.y = fmaxf(v[5], 0.f);
        hi.z = fmaxf(v[6], 0.f); hi.w = fmaxf(v[7], 0.f);
        __builtin_nontemporal_store(lo, reinterpret_cast<f32x4*>(p));
        __builtin_nontemporal_store(hi, reinterpret_cast<f32x4*>(p) + 1);
    };

    const int KS[6] = {2, 4, 8, 16, 32, 64};
#pragma unroll
    for (int fi = 0; fi < 6; ++fi) {
        const int K = KS[fi], h = (K - 1) / 2;
        float a[R], n[R];
#pragma unroll
        for (int r = 0; r < R; ++r) {
            const int dlo = r + 48 - h;         // compile-time
            const float D = Tv[dlo + K] - Tv[dlo];
            a[r] = (dlo & 1) ? D : -D;          // row fi  = -(-1)^dlo * D
            n[r] = (dlo & 1) ? -D : D;          // row fi+6 = negation
        }
        st(fi, a);
        st(fi + 6, n);
    }
#pragma unroll
    for (int f = 0; f < 5; ++f) st(12 + f, acc[f]);
}

extern "C" void kernel_launch(void* const* d_in, const int* in_sizes, int n_in,
                              void* d_out, int out_size, void* d_ws, size_t ws_size,
                              hipStream_t stream) {
    const float* x = (const float*)d_in[0];
    float* out = (float*)d_out;
    const int nbatch = in_sizes[0] / S_LEN;     // 128
    dim3 grid(S_LEN / TILE, nbatch, 1);
    conv_bank_kernel<<<grid, NTHREADS, 0, stream>>>(x, out);
}